// Round 15
// baseline (23.494 us; speedup 1.0000x reference)
//
#include <hip/hip_runtime.h>
#include <math.h>

#define B 8
#define H 384
#define W 384
#define HW (H*W)
#define NTOT (B*HW)
#define INF_I 10000
#define NFB 192            // fused BCE/dice/sumA blocks (768 thr, 1 pix/thread)
#define NVB 48             // bit-packer blocks (tgt -> column-major masks)
#define NWK 256            // row workers: (image, 12-row stripe)
#define CMB (NFB+NVB+NWK)  // combiner block id (496)
#define TOKEN 0x7E57F1A6u

// ws layout (bytes):
//   flags @ 0      : 496 lines x 256B  (fused f: line f; packer p: 192+p; worker w: 240+w)
//   slot  @ 131072 : 256 lines x 256B  (u64 loss2 partial per worker)
//   part2 @ 262144 : NFB*25 doubles (atomic-written; 17 used)
//   cw    @ 311296 : 8 img x 12 words x 384 cols u32 (147456 B, atomic-written)
//   sumA  @ 462848 : HW float (atomic-written as paired u64)
#define WS_SLOT  131072
#define WS_PART2 262144
#define WS_CW    311296
#define WS_SUMA  462848

__global__ __launch_bounds__(768) void k_all(const float* __restrict__ pred,
                                             const int* __restrict__ tgt,
                                             char* __restrict__ ws,
                                             float* __restrict__ out) {
    __shared__ float lds[12][25];
    __shared__ unsigned lcw[12][384];
    __shared__ float lfp[12][412], lfn[12][412];
    __shared__ double wpart[12];
    __shared__ double sval[25];
    __shared__ double sl2[4];
    __shared__ int tsum[8];
    int tid = threadIdx.x, bid = blockIdx.x;
    unsigned* flags = (unsigned*)ws;
    double* part2 = (double*)(ws + WS_PART2);
    unsigned* cwG = (unsigned*)(ws + WS_CW);
    float* sumA = (float*)(ws + WS_SUMA);

    if (bid < NFB) {
        // ============ fused BCE + dice partials + sumA (1 pixel/thread) ============
        int pix = bid * 768 + tid;
        float vals[17];                    // 0=bce, 1+b=p, 9+b=p*t (t-sums via popcount)
        float sA = 0.f, bce = 0.f;
#pragma unroll
        for (int b = 0; b < 8; ++b) {
            float x = pred[b * HW + pix];
            int t = tgt[b * HW + pix];
            // cheap HW transcendentals: err ~1e-7 rel, 5 orders below threshold
            float e = __builtin_amdgcn_exp2f(fabsf(x) * -1.442695041f);  // exp(-|x|)
            float rc = __builtin_amdgcn_rcpf(1.f + e);                   // 1/(1+e)
            float p = (x >= 0.f) ? rc : 1.f - rc;                        // sigmoid
            float l1p = __builtin_amdgcn_logf(1.f + e) * 0.69314718056f; // log1p(e)
            bce += fmaxf(x, 0.f) + l1p - x * (float)t;                   // softplus - x*t
            vals[1 + b] = p;
            vals[9 + b] = t ? p : 0.f;
            sA += t ? 1.f - p : p;
        }
        // paired 64-bit coherent publish of sumA (even lane writes 2 pixels)
        {
            float nxt = __shfl_down(sA, 1);
            if ((tid & 1) == 0) {
                unsigned long long pk = ((unsigned long long)__float_as_uint(nxt) << 32)
                                      | (unsigned long long)__float_as_uint(sA);
                atomicExch((unsigned long long*)&sumA[pix], pk);
            }
        }
        vals[0] = bce;
#pragma unroll
        for (int k = 0; k < 17; ++k)
#pragma unroll
            for (int o = 32; o; o >>= 1) vals[k] += __shfl_down(vals[k], o);
        int wave = tid >> 6, lane = tid & 63;
        if (lane == 0)
#pragma unroll
            for (int k = 0; k < 17; ++k) lds[wave][k] = vals[k];
        __syncthreads();
        if (tid < 17) {
            double s = 0.0;
#pragma unroll
            for (int wv = 0; wv < 12; ++wv) s += (double)lds[wv][tid];
            atomicExch((unsigned long long*)&part2[bid * 25 + tid],
                       (unsigned long long)__double_as_longlong(s));
        }
        __syncthreads();                       // drains all threads' atomics
        if (tid == 0) atomicExch(&flags[bid * 64], TOKEN);
    } else if (bid < NFB + NVB) {
        // ============ packer: tgt -> column-major 32-row bit words ============
        int p = bid - NFB;
        int wd = tid >> 6, wl = tid & 63;
        int b = p / 6, w = (p % 6) * 64 + wl;
        const int* colp = tgt + b * HW + w + (wd * 32) * W;
        unsigned m = 0;
#pragma unroll
        for (int i = 0; i < 32; ++i)
            m |= (colp[i * W] != 0) ? (1u << i) : 0u;
        atomicExch(&cwG[(b * 12 + wd) * 384 + w], m);
        __syncthreads();
        if (tid == 0) atomicExch(&flags[(192 + p) * 64], TOKEN);
    } else if (bid < CMB) {
        // ============ worker: (image b, 12-row stripe) ============
        int w = bid - (NFB + NVB);
        int b = w >> 5, stripe = w & 31;
        int h0 = stripe * 12;
        // poll packer flags only (EDT does not need sumA)
        if (tid < 6) {
            int line = (192 + 6 * b + tid) * 64;
            while (atomicAdd(&flags[line], 0u) != TOKEN) __builtin_amdgcn_s_sleep(8);
        }
        __syncthreads();
        // stage this image's bit words (18 KB, L3-hot)
        {
            const unsigned* src = cwG + b * 12 * 384;
            unsigned* dst = &lcw[0][0];
            for (int i = tid; i < 12 * 384; i += 768) dst[i] = src[i];
        }
        __syncthreads();

        // ---- vertical EDT for rows h0..h0+11, one (column, pos/neg) per thread ----
        {
            int col = tid >> 1, pn = tid & 1;
            unsigned cwv[12];
#pragma unroll
            for (int j = 0; j < 12; ++j) {
                unsigned mm = lcw[j][col];
                cwv[j] = pn ? ~mm : mm;
            }
            int wd0 = h0 >> 5, off = h0 & 31;
            // carry from above (nearest set bit at row < h0)
            int cin = INF_I;
            {
                unsigned mm = off ? (cwv[wd0] & ((1u << off) - 1u)) : 0u;
                int j = wd0;
                while (mm == 0u && j > 0) mm = cwv[--j];
                if (mm) cin = h0 - (j * 32 + (31 - __clz(mm)));
            }
            // carry from below (nearest set bit at row >= h0+12)
            int cinb = INF_I;
            int he = h0 + 12;
            if (he < H) {
                int j1 = he >> 5, off1 = he & 31;
                unsigned mm = cwv[j1] & (off1 ? ~((1u << off1) - 1u) : 0xFFFFFFFFu);
                int j = j1;
                while (mm == 0u && j < 11) mm = cwv[++j];
                if (mm) cinb = (j * 32 + (__ffs(mm) - 1)) - (h0 + 11);
            }
            unsigned lo = cwv[wd0];
            unsigned hi = (wd0 < 11) ? cwv[wd0 + 1] : 0u;
            unsigned long long win = ((((unsigned long long)hi) << 32) | lo) >> off;
            int df[12];
            int c = cin;
#pragma unroll
            for (int r = 0; r < 12; ++r) {
                c = ((win >> r) & 1ull) ? 0 : min(c + 1, INF_I);
                df[r] = c;
            }
            int cb = cinb;
            int s = col + (col >> 4);
#pragma unroll
            for (int r = 11; r >= 0; --r) {
                cb = ((win >> r) & 1ull) ? 0 : min(cb + 1, INF_I);
                int d = min(df[r], cb);
                float fd = (float)d;
                if (pn) lfn[r][s] = fd * fd;   // exact: d<=1e4 -> d^2<=1e8
                else    lfp[r][s] = fd * fd;
            }
        }
        __syncthreads();   // lfp/lfn complete for the whole stripe

        // ---- row lower-envelope into registers (sumA NOT needed yet) ----
        int wv = tid >> 6, lane = tid & 63;
        int h = h0 + wv;
        int base = 6 * lane - 8;
        float rp[22], rn[22];
#pragma unroll
        for (int r = 0; r < 22; ++r) {
            int j = base + r;
            j = j < 0 ? 0 : (j > W - 1 ? W - 1 : j);
            int s = j + (j >> 4);
            rp[r] = lfp[wv][s];
            rn[r] = lfn[wv][s];
        }
        const float DD[17] = {64.f,49.f,36.f,25.f,16.f,9.f,4.f,1.f,0.f,
                              1.f,4.f,9.f,16.f,25.f,36.f,49.f,64.f};
        float sdf6[6];
#pragma unroll
        for (int q = 0; q < 6; ++q) {
            int i = 6 * lane + q;
            float Dp = 3.0e38f, Dn = 3.0e38f;
#pragma unroll
            for (int tt = 0; tt < 17; ++tt) {
                Dp = fminf(Dp, rp[q + tt] + DD[tt]);
                Dn = fminf(Dn, rn[q + tt] + DD[tt]);
            }
            if (Dp > 64.f || Dn > 64.f) {      // exactness not proven -> full row
                float fi = (float)i;
                for (int j = 0; j < W; ++j) {
                    int s = j + (j >> 4);
                    float d = fi - (float)j;
                    Dp = fminf(Dp, fmaf(d, d, lfp[wv][s]));
                    Dn = fminf(Dn, fmaf(d, d, lfn[wv][s]));
                }
            }
            sdf6[q] = fabsf(sqrtf(Dp) - sqrtf(Dn));
        }
        // only NOW wait for the fused blocks that produce this stripe's sumA rows
        if (tid < 6) {
            int line = (6 * stripe + tid) * 64;
            while (atomicAdd(&flags[line], 0u) != TOKEN) __builtin_amdgcn_s_sleep(8);
        }
        __syncthreads();

        float partial = 0.f;
#pragma unroll
        for (int q = 0; q < 6; ++q)
            partial += sdf6[q] * sumA[h * W + 6 * lane + q];
        double v = partial;
#pragma unroll
        for (int o = 32; o; o >>= 1) v += __shfl_down(v, o);
        if (lane == 0) wpart[wv] = v;
        __syncthreads();
        if (tid == 0) {
            double bp = 0.0;
#pragma unroll
            for (int k = 0; k < 12; ++k) bp += wpart[k];
            atomicExch((unsigned long long*)(ws + WS_SLOT + w * 256),
                       (unsigned long long)__double_as_longlong(bp));
            asm volatile("s_waitcnt vmcnt(0)" ::: "memory");  // slot before flag
            atomicExch(&flags[(240 + w) * 64], TOKEN);
        }
    } else {
        // ============ combiner: poll ONLY worker flags (implies all producers) ============
        if (tid < 256) {
            int line = (240 + tid) * 64;
            while (atomicAdd(&flags[line], 0u) != TOKEN) __builtin_amdgcn_s_sleep(8);
        }
        if (tid < 8) tsum[tid] = 0;
        __syncthreads();
        // per-image t-sums: exact integer popcount of packed bits (order-free)
        {
            int b = tid / 96, idx = tid % 96;
            const unsigned* base = cwG + b * 4608 + idx * 48;
            int s = 0;
#pragma unroll 8
            for (int i = 0; i < 48; ++i) s += __popc(base[i]);
            atomicAdd(&tsum[b], s);            // LDS int atomic: exact
        }
        if (tid < 136) {
            int v = tid >> 3, sub = tid & 7;
            double s = 0.0;
            for (int blk = sub; blk < NFB; blk += 8) s += part2[blk * 25 + v];
#pragma unroll
            for (int o = 4; o; o >>= 1) s += __shfl_down(s, o, 8);
            if (sub == 0) sval[v] = s;
        }
        double s2 = 0.0;
        if (tid < 256)
            s2 = *(const double*)(ws + WS_SLOT + tid * 256);
#pragma unroll
        for (int o = 32; o; o >>= 1) s2 += __shfl_down(s2, o);
        if (tid < 256 && (tid & 63) == 0) sl2[tid >> 6] = s2;
        __syncthreads();
        if (tid == 0) {
            double bce = sval[0] / (double)NTOT;
            double dsum = 0.0;
            for (int bb = 0; bb < 8; ++bb)
                dsum += (2.0 * sval[9 + bb] + 1e-5)
                      / (sval[1 + bb] + (double)tsum[bb] + 1e-5);
            double dice = dsum / 8.0;
            double loss1 = 0.5 * bce + (1.0 - dice);
            double loss2 = (sl2[0] + sl2[1] + sl2[2] + sl2[3])
                         / ((double)B * (double)B * (double)HW);
            out[0] = (float)(0.7 * loss1 + 0.03 * loss2);
        }
    }
}

extern "C" void kernel_launch(void* const* d_in, const int* in_sizes, int n_in,
                              void* d_out, int out_size, void* d_ws, size_t ws_size,
                              hipStream_t stream) {
    const float* pred = (const float*)d_in[0];
    const int* tgt = (const int*)d_in[1];
    float* out = (float*)d_out;
    char* ws = (char*)d_ws;

    k_all<<<CMB + 1, 768, 0, stream>>>(pred, tgt, ws, out);
}

// Round 16
// 20.865 us; speedup vs baseline: 1.1260x; 1.1260x over previous
//
#include <hip/hip_runtime.h>
#include <math.h>

#define B 8
#define H 384
#define W 384
#define HW (H*W)
#define NTOT (B*HW)
#define INF_I 10000
#define NFB 192            // fused BCE/dice/sumA blocks (768 thr, 1 pix/thread)
#define NVB 48             // bit-packer blocks (tgt -> column-major masks)
#define NWK 256            // row workers: (image, 12-row stripe)
#define CMB (NFB+NVB+NWK)  // combiner block id (496)
#define TOKEN 0x7E57F1A6u

// ws layout (bytes):
//   flags @ 0      : 496 lines x 256B  (fused f: line f; packer p: 192+p; worker w: 240+w)
//   slot  @ 131072 : 256 lines x 256B  (u64 loss2 partial per worker)
//   part2 @ 262144 : NFB*25 doubles (38400 B, atomic-written)
//   cw    @ 311296 : 8 img x 12 words x 384 cols u32 (147456 B, atomic-written)
//   sumA  @ 462848 : HW float (atomic-written)
#define WS_SLOT  131072
#define WS_PART2 262144
#define WS_CW    311296
#define WS_SUMA  462848

__global__ __launch_bounds__(768) void k_all(const float* __restrict__ pred,
                                             const int* __restrict__ tgt,
                                             char* __restrict__ ws,
                                             float* __restrict__ out) {
    __shared__ float lds[12][25];
    __shared__ unsigned lcw[12][384];
    __shared__ float lfp[12][412], lfn[12][412];
    __shared__ double wpart[12];
    __shared__ double sval[25];
    __shared__ double sl2[4];
    int tid = threadIdx.x, bid = blockIdx.x;
    unsigned* flags = (unsigned*)ws;
    double* part2 = (double*)(ws + WS_PART2);
    unsigned* cwG = (unsigned*)(ws + WS_CW);
    float* sumA = (float*)(ws + WS_SUMA);

    if (bid < NFB) {
        // ============ fused BCE + dice partials + sumA (1 pixel/thread) ============
        int pix = bid * 768 + tid;
        float vals[25];                    // 0=bce, 1+b=p, 9+b=p*t, 17+b=t
        float sA = 0.f, bce = 0.f;
#pragma unroll
        for (int b = 0; b < 8; ++b) {
            float x = pred[b * HW + pix];
            int t = tgt[b * HW + pix];
            // cheap HW transcendentals: err ~1e-7 rel, 5 orders below threshold
            float e = __builtin_amdgcn_exp2f(fabsf(x) * -1.442695041f);  // exp(-|x|)
            float rc = __builtin_amdgcn_rcpf(1.f + e);                   // 1/(1+e)
            float p = (x >= 0.f) ? rc : 1.f - rc;                        // sigmoid
            float l1p = __builtin_amdgcn_logf(1.f + e) * 0.69314718056f; // log1p(e)
            bce += fmaxf(x, 0.f) + l1p - x * (float)t;                   // softplus - x*t
            vals[1 + b] = p;
            vals[9 + b] = t ? p : 0.f;
            vals[17 + b] = (float)t;
            sA += t ? 1.f - p : p;
        }
        atomicExch((unsigned*)&sumA[pix], __float_as_uint(sA));   // coherent publish
        vals[0] = bce;
#pragma unroll
        for (int k = 0; k < 25; ++k)
#pragma unroll
            for (int o = 32; o; o >>= 1) vals[k] += __shfl_down(vals[k], o);
        int wave = tid >> 6, lane = tid & 63;
        if (lane == 0)
#pragma unroll
            for (int k = 0; k < 25; ++k) lds[wave][k] = vals[k];
        __syncthreads();
        if (tid < 25) {
            double s = 0.0;
#pragma unroll
            for (int wv = 0; wv < 12; ++wv) s += (double)lds[wv][tid];
            atomicExch((unsigned long long*)&part2[bid * 25 + tid],
                       (unsigned long long)__double_as_longlong(s));
        }
        __syncthreads();                       // drains all threads' atomics
        if (tid == 0) atomicExch(&flags[bid * 64], TOKEN);
    } else if (bid < NFB + NVB) {
        // ============ packer: tgt -> column-major 32-row bit words ============
        int p = bid - NFB;
        int wd = tid >> 6, wl = tid & 63;
        int b = p / 6, w = (p % 6) * 64 + wl;
        const int* colp = tgt + b * HW + w + (wd * 32) * W;
        unsigned m = 0;
#pragma unroll
        for (int i = 0; i < 32; ++i)
            m |= (colp[i * W] != 0) ? (1u << i) : 0u;
        atomicExch(&cwG[(b * 12 + wd) * 384 + w], m);
        __syncthreads();
        if (tid == 0) atomicExch(&flags[(192 + p) * 64], TOKEN);
    } else if (bid < CMB) {
        // ============ worker: (image b, 12-row stripe) ============
        int w = bid - (NFB + NVB);
        int b = w >> 5, stripe = w & 31;
        int h0 = stripe * 12;
        // poll packer flags only (EDT does not need sumA yet)
        if (tid < 6) {
            int line = (192 + 6 * b + tid) * 64;
            while (atomicAdd(&flags[line], 0u) != TOKEN) __builtin_amdgcn_s_sleep(8);
        }
        __syncthreads();
        // stage this image's bit words (18 KB, L3-hot)
        {
            const unsigned* src = cwG + b * 12 * 384;
            unsigned* dst = &lcw[0][0];
            for (int i = tid; i < 12 * 384; i += 768) dst[i] = src[i];
        }
        __syncthreads();

        // ---- vertical EDT for rows h0..h0+11, one (column, pos/neg) per thread ----
        {
            int col = tid >> 1, pn = tid & 1;
            unsigned cwv[12];
#pragma unroll
            for (int j = 0; j < 12; ++j) {
                unsigned mm = lcw[j][col];
                cwv[j] = pn ? ~mm : mm;
            }
            int wd0 = h0 >> 5, off = h0 & 31;
            // carry from above (nearest set bit at row < h0)
            int cin = INF_I;
            {
                unsigned mm = off ? (cwv[wd0] & ((1u << off) - 1u)) : 0u;
                int j = wd0;
                while (mm == 0u && j > 0) mm = cwv[--j];
                if (mm) cin = h0 - (j * 32 + (31 - __clz(mm)));
            }
            // carry from below (nearest set bit at row >= h0+12)
            int cinb = INF_I;
            int he = h0 + 12;
            if (he < H) {
                int j1 = he >> 5, off1 = he & 31;
                unsigned mm = cwv[j1] & (off1 ? ~((1u << off1) - 1u) : 0xFFFFFFFFu);
                int j = j1;
                while (mm == 0u && j < 11) mm = cwv[++j];
                if (mm) cinb = (j * 32 + (__ffs(mm) - 1)) - (h0 + 11);
            }
            unsigned lo = cwv[wd0];
            unsigned hi = (wd0 < 11) ? cwv[wd0 + 1] : 0u;
            unsigned long long win = ((((unsigned long long)hi) << 32) | lo) >> off;
            int df[12];
            int c = cin;
#pragma unroll
            for (int r = 0; r < 12; ++r) {
                c = ((win >> r) & 1ull) ? 0 : min(c + 1, INF_I);
                df[r] = c;
            }
            int cb = cinb;
            int s = col + (col >> 4);
#pragma unroll
            for (int r = 11; r >= 0; --r) {
                cb = ((win >> r) & 1ull) ? 0 : min(cb + 1, INF_I);
                int d = min(df[r], cb);
                float fd = (float)d;
                if (pn) lfn[r][s] = fd * fd;   // exact: d<=1e4 -> d^2<=1e8
                else    lfp[r][s] = fd * fd;
            }
        }
        // now wait for the fused blocks that produce this stripe's sumA rows
        if (tid < 6) {
            int line = (6 * stripe + tid) * 64;
            while (atomicAdd(&flags[line], 0u) != TOKEN) __builtin_amdgcn_s_sleep(8);
        }
        __syncthreads();   // orders EDT LDS writes AND the sumA flag wait

        // ---- row lower-envelope (17-tap window + provable full-row fallback) ----
        int wv = tid >> 6, lane = tid & 63;
        int h = h0 + wv;
        int base = 6 * lane - 8;
        float rp[22], rn[22];
#pragma unroll
        for (int r = 0; r < 22; ++r) {
            int j = base + r;
            j = j < 0 ? 0 : (j > W - 1 ? W - 1 : j);
            int s = j + (j >> 4);
            rp[r] = lfp[wv][s];
            rn[r] = lfn[wv][s];
        }
        const float DD[17] = {64.f,49.f,36.f,25.f,16.f,9.f,4.f,1.f,0.f,
                              1.f,4.f,9.f,16.f,25.f,36.f,49.f,64.f};
        float partial = 0.f;
#pragma unroll
        for (int q = 0; q < 6; ++q) {
            int i = 6 * lane + q;
            float Dp = 3.0e38f, Dn = 3.0e38f;
#pragma unroll
            for (int tt = 0; tt < 17; ++tt) {
                Dp = fminf(Dp, rp[q + tt] + DD[tt]);
                Dn = fminf(Dn, rn[q + tt] + DD[tt]);
            }
            if (Dp > 64.f || Dn > 64.f) {      // exactness not proven -> full row
                float fi = (float)i;
                for (int j = 0; j < W; ++j) {
                    int s = j + (j >> 4);
                    float d = fi - (float)j;
                    Dp = fminf(Dp, fmaf(d, d, lfp[wv][s]));
                    Dn = fminf(Dn, fmaf(d, d, lfn[wv][s]));
                }
            }
            float sdf = fabsf(sqrtf(Dp) - sqrtf(Dn));
            partial += sdf * sumA[h * W + i];
        }
        double v = partial;
#pragma unroll
        for (int o = 32; o; o >>= 1) v += __shfl_down(v, o);
        if (lane == 0) wpart[wv] = v;
        __syncthreads();
        if (tid == 0) {
            double bp = 0.0;
#pragma unroll
            for (int k = 0; k < 12; ++k) bp += wpart[k];
            atomicExch((unsigned long long*)(ws + WS_SLOT + w * 256),
                       (unsigned long long)__double_as_longlong(bp));
            asm volatile("s_waitcnt vmcnt(0)" ::: "memory");  // slot before flag
            atomicExch(&flags[(240 + w) * 64], TOKEN);
        }
    } else {
        // ============ combiner ============
        if (tid < 448) {
            int line = (tid < 192) ? tid * 64 : (240 + (tid - 192)) * 64;
            while (atomicAdd(&flags[line], 0u) != TOKEN) __builtin_amdgcn_s_sleep(8);
        }
        __syncthreads();
        if (tid < 200) {
            int v = tid >> 3, sub = tid & 7;
            double s = 0.0;
            for (int blk = sub; blk < NFB; blk += 8) s += part2[blk * 25 + v];
#pragma unroll
            for (int o = 4; o; o >>= 1) s += __shfl_down(s, o, 8);
            if (sub == 0) sval[v] = s;
        }
        double s2 = 0.0;
        if (tid < 256)
            s2 = *(const double*)(ws + WS_SLOT + tid * 256);
#pragma unroll
        for (int o = 32; o; o >>= 1) s2 += __shfl_down(s2, o);
        if (tid < 256 && (tid & 63) == 0) sl2[tid >> 6] = s2;
        __syncthreads();
        if (tid == 0) {
            double bce = sval[0] / (double)NTOT;
            double dsum = 0.0;
            for (int bb = 0; bb < 8; ++bb)
                dsum += (2.0 * sval[9 + bb] + 1e-5) / (sval[1 + bb] + sval[17 + bb] + 1e-5);
            double dice = dsum / 8.0;
            double loss1 = 0.5 * bce + (1.0 - dice);
            double loss2 = (sl2[0] + sl2[1] + sl2[2] + sl2[3])
                         / ((double)B * (double)B * (double)HW);
            out[0] = (float)(0.7 * loss1 + 0.03 * loss2);
        }
    }
}

extern "C" void kernel_launch(void* const* d_in, const int* in_sizes, int n_in,
                              void* d_out, int out_size, void* d_ws, size_t ws_size,
                              hipStream_t stream) {
    const float* pred = (const float*)d_in[0];
    const int* tgt = (const int*)d_in[1];
    float* out = (float*)d_out;
    char* ws = (char*)d_ws;

    k_all<<<CMB + 1, 768, 0, stream>>>(pred, tgt, ws, out);
}